// Round 4
// baseline (495.090 us; speedup 1.0000x reference)
//
#include <hip/hip_runtime.h>

typedef unsigned short u16;
typedef unsigned int u32;

#define NEG_SLOPE 0.2f

using short8 = __attribute__((ext_vector_type(8))) short;
using float4v = __attribute__((ext_vector_type(4))) float;

__device__ __forceinline__ float bfu(u16 v) { return __uint_as_float(((u32)v) << 16); }
__device__ __forceinline__ float bflo(u32 u) { return __uint_as_float(u << 16); }
__device__ __forceinline__ float bfhi(u32 u) { return __uint_as_float(u & 0xffff0000u); }
__device__ __forceinline__ u16 f2bf(float f) {
  u32 x = __float_as_uint(f);
  return (u16)((x + 0x7fffu + ((x >> 16) & 1u)) >> 16);
}
__device__ __forceinline__ float loadf(const void* p, int idx, int isbf) {
  return isbf ? bfu(((const u16*)p)[idx]) : ((const float*)p)[idx];
}

// physical XCD id (HW_REG_XCC_ID = 20, gfx940+; m09-verified). Wave-uniform SGPR.
__device__ __forceinline__ int xcc_id() {
  unsigned v;
  asm volatile("s_getreg_b32 %0, hwreg(20, 0, 8)" : "=s"(v));
  return (int)(v & 7u);
}

// ---------------- dtype detection (bf16 vs f32 inputs) ----------------
__global__ __launch_bounds__(256) void detect_dtype(const u32* __restrict__ w,
                                                    int nwords, int* __restrict__ flag) {
  __shared__ int cnt;
  if (threadIdx.x == 0) cnt = 0;
  __syncthreads();
  int c = 0;
  for (int i = threadIdx.x; i < nwords; i += 256) {
    u32 e = (w[i] >> 7) & 0xFFu;  // exponent of low-half-as-bf16
    c += (e >= 0x60u && e <= 0x90u) ? 1 : 0;
  }
  atomicAdd(&cnt, c);
  __syncthreads();
  if (threadIdx.x == 0) flag[0] = (cnt * 2 > nwords) ? 1 : 0;  // 1 = bf16
}

__global__ __launch_bounds__(256) void zero_i32(int* __restrict__ p, int n) {
  int i = blockIdx.x * 256 + threadIdx.x;
  if (i < n) p[i] = 0;
}

// ---------------- scans ----------------

// scan1 folds the 8 per-XCD histogram replicas:
//   reads cnt8[r*N+idx], writes back the per-replica exclusive offset (within node),
//   and scans the per-node total.
__global__ __launch_bounds__(256) void scan1(int* __restrict__ cnt8,
                                             int* __restrict__ indptr,
                                             int* __restrict__ bsum, int N) {
  __shared__ int sh[256];
  int t = threadIdx.x;
  int idx = blockIdx.x * 256 + t;
  int v = 0;
  if (idx < N) {
    int s = 0;
#pragma unroll
    for (int r = 0; r < 8; ++r) {
      int c = cnt8[r * N + idx];
      cnt8[r * N + idx] = s;  // exclusive offset of replica r within node idx
      s += c;
    }
    v = s;
  }
  sh[t] = v;
  __syncthreads();
  for (int off = 1; off < 256; off <<= 1) {
    int y = (t >= off) ? sh[t - off] : 0;
    __syncthreads();
    sh[t] += y;
    __syncthreads();
  }
  if (idx < N) indptr[idx] = sh[t] - v;  // exclusive, pre-offset
  if (t == 255) bsum[blockIdx.x] = sh[255];
}

// parallel single-block exclusive scan of block sums (NB <= 512)
__global__ __launch_bounds__(512) void scan2par(int* __restrict__ bsum, int NB) {
  __shared__ int sh[512];
  int t = threadIdx.x;
  int v = (t < NB) ? bsum[t] : 0;
  sh[t] = v;
  __syncthreads();
  for (int off = 1; off < 512; off <<= 1) {
    int y = (t >= off) ? sh[t - off] : 0;
    __syncthreads();
    sh[t] += y;
    __syncthreads();
  }
  if (t < NB) bsum[t] = sh[t] - v;  // exclusive
}

__global__ __launch_bounds__(256) void scan3(int* __restrict__ indptr,
                                             const int* __restrict__ boff,
                                             int N, int E) {
  int idx = blockIdx.x * 256 + threadIdx.x;
  if (idx < N) indptr[idx] += boff[blockIdx.x];
  if (idx == 0) indptr[N] = E;
}

// ---------------- scatter without atomics (uses precomputed replica+rank) --------
__global__ __launch_bounds__(256) void scatter2(const int* __restrict__ src,
                                                const int* __restrict__ dst,
                                                const int* __restrict__ rank,
                                                const int* __restrict__ indptr,
                                                const int* __restrict__ cnt8,
                                                int* __restrict__ ssrc, int E, int N) {
  int e = blockIdx.x * 256 + threadIdx.x;
  if (e < E) {
    int d = dst[e];
    u32 rk = (u32)rank[e];
    int rep = (int)(rk >> 28);
    int lr = (int)(rk & 0x0FFFFFFFu);
    ssrc[indptr[d] + cnt8[rep * N + d] + lr] = src[e];
  }
}

// ---------------- B-fragment swizzle buffer ----------------
__global__ __launch_bounds__(256) void bsw_build(const void* __restrict__ W,
                                                 u16* __restrict__ Bsw, int K,
                                                 const int* __restrict__ dflag) {
  const int isbf = dflag[0];
  int t = blockIdx.x * 256 + threadIdx.x;
  int total = (K / 32) * 8 * 64;
  if (t >= total) return;
  int lane = t & 63;
  int c = (t >> 6) & 7;
  int ktile = t >> 9;
  int n = lane & 15, q = lane >> 4;
  int col = c * 16 + n;
  u16 vals[8];
#pragma unroll
  for (int j = 0; j < 8; ++j) {
    int k = ktile * 32 + q * 8 + j;
    int idx = col * K + k;
    vals[j] = isbf ? ((const u16*)W)[idx] : f2bf(((const float*)W)[idx]);
  }
  *(uint4*)(Bsw + (size_t)t * 8) = *(uint4*)vals;
}

// ---------------- MFMA GEMM body: 32 rows/wave (2 row-tiles), 128 rows/block ----
// Round-4 restructure: each B fragment loaded once feeds 2 MFMAs (2 row-tiles),
// halving per-wave B re-read traffic and doubling independent A-loads in flight.
// acc[2][8] = 64 VGPR; total ~115 VGPR -> 4 waves/SIMD class.
template <int K, int DYNA>
__device__ __forceinline__ void gemm_body(int bix, const void* __restrict__ Xv,
                                          const u16* __restrict__ Bsw,
                                          u16* __restrict__ Hb,
                                          const void* __restrict__ al,
                                          const void* __restrict__ ar,
                                          float* __restrict__ el_,
                                          float* __restrict__ er_, int N,
                                          const int* __restrict__ dflag) {
  const int isbfP = dflag[0];
  const int isbfA = DYNA ? isbfP : 1;  // x intermediate is always bf16
  int tid = threadIdx.x;
  int w = tid >> 6, lane = tid & 63;
  int n = lane & 15, q = lane >> 4;
  int base = bix * 128 + w * 32;  // wave covers rows [base, base+32)

  int mclamp[2];
#pragma unroll
  for (int mt = 0; mt < 2; ++mt) {
    int m = base + mt * 16 + n;
    mclamp[mt] = (m < N) ? m : 0;
  }

  float alv[8], arv[8];
#pragma unroll
  for (int c = 0; c < 8; ++c) {
    alv[c] = loadf(al, c * 16 + n, isbfP);
    arv[c] = loadf(ar, c * 16 + n, isbfP);
  }

  float4v acc[2][8];
#pragma unroll
  for (int mt = 0; mt < 2; ++mt)
#pragma unroll
    for (int c = 0; c < 8; ++c) acc[mt][c] = (float4v){0.f, 0.f, 0.f, 0.f};

#pragma unroll
  for (int t = 0; t < K / 32; ++t) {
    short8 af[2];
#pragma unroll
    for (int mt = 0; mt < 2; ++mt) {
      if (isbfA) {
        af[mt] = *(const short8*)((const u16*)Xv + (size_t)mclamp[mt] * K + t * 32 + q * 8);
      } else {
        const float* Af = (const float*)Xv + (size_t)mclamp[mt] * K + t * 32 + q * 8;
        float4 f0 = *(const float4*)Af;
        float4 f1 = *(const float4*)(Af + 4);
        u16 tmp[8] = {f2bf(f0.x), f2bf(f0.y), f2bf(f0.z), f2bf(f0.w),
                      f2bf(f1.x), f2bf(f1.y), f2bf(f1.z), f2bf(f1.w)};
        af[mt] = *(short8*)tmp;
      }
    }
    const uint4* bt = (const uint4*)Bsw + ((size_t)t * 8) * 64 + lane;
#pragma unroll
    for (int c = 0; c < 8; ++c) {
      uint4 bw = bt[c * 64];
      short8 bf = *(short8*)&bw;
      acc[0][c] = __builtin_amdgcn_mfma_f32_16x16x32_bf16(af[0], bf, acc[0][c], 0, 0, 0);
      acc[1][c] = __builtin_amdgcn_mfma_f32_16x16x32_bf16(af[1], bf, acc[1][c], 0, 0, 0);
    }
  }

  // Hb store: D layout col = c*16 + (lane&15), row = base + mt*16 + q*4 + r
  // (direct u16 stores; L2 merges them — verified round 1)
#pragma unroll
  for (int mt = 0; mt < 2; ++mt)
#pragma unroll
    for (int c = 0; c < 8; ++c) {
#pragma unroll
      for (int r = 0; r < 4; ++r) {
        int row = base + mt * 16 + q * 4 + r;
        if (row < N) Hb[(size_t)row * 128 + c * 16 + n] = f2bf(acc[mt][c][r]);
      }
    }

  // fused el/er: reduce across the 16 lanes of each quad-row group
#pragma unroll
  for (int mt = 0; mt < 2; ++mt)
#pragma unroll
    for (int r = 0; r < 4; ++r) {
      float sl = 0.f, sr = 0.f;
#pragma unroll
      for (int c = 0; c < 8; ++c) {
        float v = acc[mt][c][r];
        sl = fmaf(v, alv[c], sl);
        sr = fmaf(v, arv[c], sr);
      }
#pragma unroll
      for (int off = 1; off < 16; off <<= 1) {
        sl += __shfl_xor(sl, off);
        sr += __shfl_xor(sr, off);
      }
      if (n == 0) {
        int row = base + mt * 16 + q * 4 + r;
        if (row < N) {
          el_[row] = sl;
          er_[row] = sr;
        }
      }
    }
}

template <int K, int DYNA>
__global__ __launch_bounds__(256) void gemm_mfma(const void* __restrict__ Xv,
                                                 const u16* __restrict__ Bsw,
                                                 u16* __restrict__ Hb,
                                                 const void* __restrict__ al,
                                                 const void* __restrict__ ar,
                                                 float* __restrict__ el_,
                                                 float* __restrict__ er_, int N,
                                                 const int* __restrict__ dflag) {
  gemm_body<K, DYNA>(blockIdx.x, Xv, Bsw, Hb, al, ar, el_, er_, N, dflag);
}

// fused: blocks [0, gemm_blocks) do GEMM layer 1; the rest do hist+rank.
// hist: per-XCD replicated counters; inline-asm global_atomic_add with sc0
// (return old). Correct because replica r is only touched from physical XCD r;
// end-of-dispatch release publishes to scan1.
template <int K, int DYNA>
__global__ __launch_bounds__(256) void fused_gemm_hist(
    const void* __restrict__ Xv, const u16* __restrict__ Bsw, u16* __restrict__ Hb,
    const void* __restrict__ al, const void* __restrict__ ar,
    float* __restrict__ el_, float* __restrict__ er_, int N,
    const int* __restrict__ dflag, int gemm_blocks,
    const int* __restrict__ dst, int* __restrict__ cnt8,
    int* __restrict__ rank, int E) {
  int bix = (int)blockIdx.x;
  if (bix < gemm_blocks) {
    gemm_body<K, DYNA>(bix, Xv, Bsw, Hb, al, ar, el_, er_, N, dflag);
    return;
  }
  int base = (bix - gemm_blocks) * 1024 + (int)threadIdx.x * 4;
  int rep = xcc_id();
  int* cbase = cnt8 + rep * N;
  int rt = rep << 28;
  int one = 1;
  if (base + 3 < E) {
    int4 dv = *(const int4*)(dst + base);
    int* p0 = &cbase[dv.x];
    int* p1 = &cbase[dv.y];
    int* p2 = &cbase[dv.z];
    int* p3 = &cbase[dv.w];
    int r0, r1, r2, r3;
    asm volatile(
        "global_atomic_add %0, %4, %8, off sc0\n\t"
        "global_atomic_add %1, %5, %8, off sc0\n\t"
        "global_atomic_add %2, %6, %8, off sc0\n\t"
        "global_atomic_add %3, %7, %8, off sc0\n\t"
        "s_waitcnt vmcnt(0)"
        : "=&v"(r0), "=&v"(r1), "=&v"(r2), "=&v"(r3)
        : "v"(p0), "v"(p1), "v"(p2), "v"(p3), "v"(one)
        : "memory");
    *(int4*)(rank + base) = make_int4(r0 | rt, r1 | rt, r2 | rt, r3 | rt);
  } else {
    for (int j = 0; j < 4; ++j) {
      int e = base + j;
      if (e < E) {
        int* pp = &cbase[dst[e]];
        int old;
        asm volatile(
            "global_atomic_add %0, %1, %2, off sc0\n\t"
            "s_waitcnt vmcnt(0)"
            : "=&v"(old)
            : "v"(pp), "v"(one)
            : "memory");
        rank[e] = rt | old;
      }
    }
  }
}

// ---------------- aggregation v2: two-phase wave-parallel softmax ----------------
// One wave per dst node. Phase 1: up to 64 edges scored lane-parallel. Phase 2:
// broadcast (id_e, pe_e) via readlane and accumulate aa += pe_e * Hb[id_e].
template <int MODE>
__global__ __launch_bounds__(256) void agg_kernel(const u32* __restrict__ Hb,
                                                  const float* __restrict__ el,
                                                  const float* __restrict__ er,
                                                  const int* __restrict__ indptr,
                                                  const int* __restrict__ ssrc,
                                                  const void* __restrict__ bias,
                                                  void* __restrict__ outv, int N,
                                                  const int* __restrict__ dflag) {
  const int isbf = dflag[0];
  int tid = threadIdx.x;
  int n = blockIdx.x * 4 + (tid >> 6);
  int lane = tid & 63;
  if (n >= N) return;

  int beg = indptr[n];
  int end = indptr[n + 1];
  float ern = er[n];

  float aa0 = 0.f, aa1 = 0.f;
  float m_run = -INFINITY, l_run = 0.f;

  for (int p = beg; p < end; p += 64) {
    int rem = end - p;  // >= 1
    int valid = lane < rem;
    int ide = valid ? ssrc[p + lane] : 0;

    // lane-parallel scores
    float sc = el[ide] + ern;
    sc = (sc > 0.f) ? sc : NEG_SLOPE * sc;
    sc = valid ? sc : -INFINITY;

    // wave max
    float mc = sc;
#pragma unroll
    for (int off = 1; off < 64; off <<= 1) mc = fmaxf(mc, __shfl_xor(mc, off));

    float m_new = fmaxf(m_run, mc);
    float corr = __expf(m_run - m_new);  // first chunk: exp(-inf)=0
    float pe = __expf(sc - m_new);       // invalid lanes: exp(-inf)=0

    // wave sum of pe
    float ls = pe;
#pragma unroll
    for (int off = 1; off < 64; off <<= 1) ls += __shfl_xor(ls, off);

    l_run = l_run * corr + ls;
    aa0 *= corr;
    aa1 *= corr;
    m_run = m_new;

    // phase 2: gather-accumulate, 4-deep unroll for MLP
    int cl = (rem < 64) ? rem : 64;
    int e = 0;
    for (; e + 4 <= cl; e += 4) {
      int i0 = __builtin_amdgcn_readlane(ide, e);
      int i1 = __builtin_amdgcn_readlane(ide, e + 1);
      int i2 = __builtin_amdgcn_readlane(ide, e + 2);
      int i3 = __builtin_amdgcn_readlane(ide, e + 3);
      u32 h0 = Hb[(size_t)i0 * 64 + lane];
      u32 h1 = Hb[(size_t)i1 * 64 + lane];
      u32 h2 = Hb[(size_t)i2 * 64 + lane];
      u32 h3 = Hb[(size_t)i3 * 64 + lane];
      float p0 = __int_as_float(__builtin_amdgcn_readlane(__float_as_int(pe), e));
      float p1 = __int_as_float(__builtin_amdgcn_readlane(__float_as_int(pe), e + 1));
      float p2 = __int_as_float(__builtin_amdgcn_readlane(__float_as_int(pe), e + 2));
      float p3 = __int_as_float(__builtin_amdgcn_readlane(__float_as_int(pe), e + 3));
      aa0 = fmaf(p0, bflo(h0), aa0);
      aa1 = fmaf(p0, bfhi(h0), aa1);
      aa0 = fmaf(p1, bflo(h1), aa0);
      aa1 = fmaf(p1, bfhi(h1), aa1);
      aa0 = fmaf(p2, bflo(h2), aa0);
      aa1 = fmaf(p2, bfhi(h2), aa1);
      aa0 = fmaf(p3, bflo(h3), aa0);
      aa1 = fmaf(p3, bfhi(h3), aa1);
    }
    for (; e < cl; ++e) {
      int i0 = __builtin_amdgcn_readlane(ide, e);
      u32 h0 = Hb[(size_t)i0 * 64 + lane];
      float p0 = __int_as_float(__builtin_amdgcn_readlane(__float_as_int(pe), e));
      aa0 = fmaf(p0, bflo(h0), aa0);
      aa1 = fmaf(p0, bfhi(h0), aa1);
    }
  }

  float inv = (l_run > 0.f) ? 1.f / l_run : 0.f;
  float o0 = aa0 * inv + loadf(bias, 2 * lane, isbf);
  float o1 = aa1 * inv + loadf(bias, 2 * lane + 1, isbf);

  if (MODE == 0) {
    o0 = (o0 > 0.f) ? o0 : (__expf(o0) - 1.f);
    o1 = (o1 > 0.f) ? o1 : (__expf(o1) - 1.f);
    ((u32*)outv)[(size_t)n * 64 + lane] = (u32)f2bf(o0) | ((u32)f2bf(o1) << 16);
  } else {
    if (isbf) {
      ((u32*)outv)[(size_t)n * 64 + lane] = (u32)f2bf(o0) | ((u32)f2bf(o1) << 16);
    } else {
      ((float2*)outv)[(size_t)n * 64 + lane] = make_float2(o0, o1);
    }
  }
}

// ---------------- launch ----------------

extern "C" void kernel_launch(void* const* d_in, const int* in_sizes, int n_in,
                              void* d_out, int out_size, void* d_ws, size_t ws_size,
                              hipStream_t stream) {
  const int IN_FEATS = 256, HID = 128;
  const void* features = d_in[0];
  const int* src = (const int*)d_in[1];
  const int* dst = (const int*)d_in[2];
  const void* W1 = d_in[3];
  const void* al1 = d_in[4];
  const void* ar1 = d_in[5];
  const void* b1 = d_in[6];
  const void* W2 = d_in[7];
  const void* al2 = d_in[8];
  const void* ar2 = d_in[9];
  const void* b2 = d_in[10];

  const int N = in_sizes[0] / IN_FEATS;  // 100000
  const int E = in_sizes[1];             // 1600000

  char* p = (char*)d_ws;
  auto alloc = [&](size_t bytes) -> void* {
    void* q = (void*)p;
    p += (bytes + 255) & ~(size_t)255;
    return q;
  };
  int* dflag = (int*)alloc(256);
  u16* Bsw1 = (u16*)alloc((size_t)(IN_FEATS / 32) * 8 * 64 * 8 * 2);  // 64 KB
  u16* Bsw2 = (u16*)alloc((size_t)(HID / 32) * 8 * 64 * 8 * 2);       // 32 KB
  u16* hb = (u16*)alloc((size_t)N * HID * 2);  // 25.6 MB
  u16* x = (u16*)alloc((size_t)N * HID * 2);   // 25.6 MB
  float* el = (float*)alloc((size_t)N * 4);
  float* er = (float*)alloc((size_t)N * 4);
  int* cnt8 = (int*)alloc((size_t)8 * N * 4);  // 3.2 MB (8 per-XCD replicas)
  int* indptr = (int*)alloc((size_t)(N + 1) * 4);
  int* rank = (int*)alloc((size_t)E * 4);      // 6.4 MB
  int* bsum = (int*)alloc((size_t)((N + 255) / 256) * 4);
  int* ssrc = (int*)alloc((size_t)E * 4);

  const int NB = (N + 255) / 256;      // 391 (<= 512 for scan2par)
  const int EB = (E + 255) / 256;      // 6250
  const int HEB = (E + 1023) / 1024;   // 1563 (hist: 4 edges/thread)
  const int GEMM_B = (N + 127) / 128;  // 782 (128 rows/block)
  const int NODE_B = (N + 3) / 4;      // 25000

  detect_dtype<<<1, 256, 0, stream>>>((const u32*)features, 4096, dflag);
  zero_i32<<<(8 * N + 255) / 256, 256, 0, stream>>>(cnt8, 8 * N);
  bsw_build<<<((IN_FEATS / 32) * 8 * 64 + 255) / 256, 256, 0, stream>>>(W1, Bsw1, IN_FEATS, dflag);
  bsw_build<<<((HID / 32) * 8 * 64 + 255) / 256, 256, 0, stream>>>(W2, Bsw2, HID, dflag);

  // GEMM layer 1 (+ fused el/er) co-scheduled with hist+rank (independent work)
  fused_gemm_hist<IN_FEATS, 1><<<GEMM_B + HEB, 256, 0, stream>>>(
      features, Bsw1, hb, al1, ar1, el, er, N, dflag, GEMM_B, dst, cnt8, rank, E);

  scan1<<<NB, 256, 0, stream>>>(cnt8, indptr, bsum, N);
  scan2par<<<1, 512, 0, stream>>>(bsum, NB);
  scan3<<<NB, 256, 0, stream>>>(indptr, bsum, N, E);
  scatter2<<<EB, 256, 0, stream>>>(src, dst, rank, indptr, cnt8, ssrc, E, N);

  agg_kernel<0><<<NODE_B, 256, 0, stream>>>((const u32*)hb, el, er, indptr, ssrc, b1, (void*)x, N, dflag);

  gemm_mfma<HID, 0><<<GEMM_B, 256, 0, stream>>>((const void*)x, Bsw2, hb, al2, ar2, el, er, N, dflag);
  agg_kernel<1><<<NODE_B, 256, 0, stream>>>((const u32*)hb, el, er, indptr, ssrc, b2, d_out, N, dflag);
}

// Round 7
// 481.024 us; speedup vs baseline: 1.0292x; 1.0292x over previous
//
#include <hip/hip_runtime.h>

typedef unsigned short u16;
typedef unsigned int u32;

#define NEG_SLOPE 0.2f
#define BSHIFT 8
#define MAXBUCK 1024  // supports N up to 262144

using short8 = __attribute__((ext_vector_type(8))) short;
using float4v = __attribute__((ext_vector_type(4))) float;

__device__ __forceinline__ float bfu(u16 v) { return __uint_as_float(((u32)v) << 16); }
__device__ __forceinline__ float bflo(u32 u) { return __uint_as_float(u << 16); }
__device__ __forceinline__ float bfhi(u32 u) { return __uint_as_float(u & 0xffff0000u); }
__device__ __forceinline__ u16 f2bf(float f) {
  u32 x = __float_as_uint(f);
  return (u16)((x + 0x7fffu + ((x >> 16) & 1u)) >> 16);
}
__device__ __forceinline__ float loadf(const void* p, int idx, int isbf) {
  return isbf ? bfu(((const u16*)p)[idx]) : ((const float*)p)[idx];
}

// ---------------- dtype detection (bf16 vs f32 inputs) ----------------
__global__ __launch_bounds__(256) void detect_dtype(const u32* __restrict__ w,
                                                    int nwords, int* __restrict__ flag) {
  __shared__ int cnt;
  if (threadIdx.x == 0) cnt = 0;
  __syncthreads();
  int c = 0;
  for (int i = threadIdx.x; i < nwords; i += 256) {
    u32 e = (w[i] >> 7) & 0xFFu;  // exponent of low-half-as-bf16
    c += (e >= 0x60u && e <= 0x90u) ? 1 : 0;
  }
  atomicAdd(&cnt, c);
  __syncthreads();
  if (threadIdx.x == 0) flag[0] = (cnt * 2 > nwords) ? 1 : 0;  // 1 = bf16
}

// ---------------- generic scan kernels (for Gh, M up to ~160K) ----------------
__global__ __launch_bounds__(256) void scanA(int* __restrict__ a,
                                             int* __restrict__ bsum, int M) {
  __shared__ int sh[256];
  int t = threadIdx.x;
  int idx = blockIdx.x * 256 + t;
  int v = (idx < M) ? a[idx] : 0;
  sh[t] = v;
  __syncthreads();
  for (int off = 1; off < 256; off <<= 1) {
    int y = (t >= off) ? sh[t - off] : 0;
    __syncthreads();
    sh[t] += y;
    __syncthreads();
  }
  if (idx < M) a[idx] = sh[t] - v;  // exclusive, pre-offset
  if (t == 255) bsum[blockIdx.x] = sh[255];
}

// single-block sequential-chunk exclusive scan (any MB)
__global__ __launch_bounds__(512) void scanBseq(int* __restrict__ a, int MB) {
  __shared__ int sh[512];
  __shared__ int carry;
  int t = threadIdx.x;
  if (t == 0) carry = 0;
  __syncthreads();
  for (int base = 0; base < MB; base += 512) {
    int v = (base + t < MB) ? a[base + t] : 0;
    sh[t] = v;
    __syncthreads();
    for (int off = 1; off < 512; off <<= 1) {
      int y = (t >= off) ? sh[t - off] : 0;
      __syncthreads();
      sh[t] += y;
      __syncthreads();
    }
    int c0 = carry;
    int excl = sh[t] - v + c0;
    int tot = sh[511];
    __syncthreads();
    if (t == 0) carry = c0 + tot;
    if (base + t < MB) a[base + t] = excl;
    __syncthreads();
  }
}

__global__ __launch_bounds__(256) void scanC(int* __restrict__ a,
                                             const int* __restrict__ boff, int M) {
  int idx = blockIdx.x * 256 + threadIdx.x;
  if (idx < M) a[idx] += boff[blockIdx.x];
}

// ---------------- P1c: partition (dst,src) into coarse-bucket-major order -------
// Block blk re-reads its 4096 edges; LDS cursors seeded from scanned Gh give each
// (bucket,block) group a disjoint destination range. LDS atomics only.
// HARDENED (r7): bucket index and slot are unsigned-clamped — any latent bug
// becomes contained wrong output (diagnosable), never an OOB write.
__global__ __launch_bounds__(256) void part_scatter(const int* __restrict__ src,
                                                    const int* __restrict__ dst,
                                                    const int* __restrict__ Gh,
                                                    int* __restrict__ pd,
                                                    int* __restrict__ ps,
                                                    int E, int PB, int nbuck) {
  __shared__ int cur[MAXBUCK];
  int t = threadIdx.x;
  int blk = blockIdx.x;
  for (int i = t; i < nbuck; i += 256) cur[i] = Gh[(size_t)i * PB + blk];
  __syncthreads();
  int pbase = blk * 4096;
#pragma unroll
  for (int j = 0; j < 16; ++j) {
    int e = pbase + j * 256 + t;
    if (e < E) {
      int d = dst[e];
      int s = src[e];
      u32 b = (u32)d >> BSHIFT;
      if (b < (u32)nbuck) {
        int slot = atomicAdd(&cur[b], 1);
        if ((u32)slot < (u32)E) {
          pd[slot] = d;
          ps[slot] = s;
        }
      }
    }
  }
}

// ---------------- P2: per-bucket fine counting sort + indptr ----------------
// Block b owns dst nodes [b*256, b*256+256). Counts into 256 LDS bins, LDS scan
// -> indptr, then LDS-cursor scatter of ssrc (writes within a hot 16KB window).
// HARDENED (r7): scatter slot unsigned-clamped against E.
__global__ __launch_bounds__(256) void bucket_sort(const int* __restrict__ pd,
                                                   const int* __restrict__ ps,
                                                   const int* __restrict__ Gh,
                                                   int* __restrict__ indptr,
                                                   int* __restrict__ ssrc,
                                                   int E, int N, int PB, int nbuck) {
  __shared__ int bins[256];
  __shared__ int sh[256];
  __shared__ int cur[256];
  int t = threadIdx.x;
  int b = blockIdx.x;
  int base = Gh[(size_t)b * PB];
  int nextb = (b + 1 < nbuck) ? Gh[(size_t)(b + 1) * PB] : E;
  int sz = nextb - base;

  bins[t] = 0;
  __syncthreads();
  for (int i = t; i < sz; i += 256) atomicAdd(&bins[pd[base + i] & 255], 1);
  __syncthreads();

  int v = bins[t];
  sh[t] = v;
  __syncthreads();
  for (int off = 1; off < 256; off <<= 1) {
    int y = (t >= off) ? sh[t - off] : 0;
    __syncthreads();
    sh[t] += y;
    __syncthreads();
  }
  int excl = sh[t] - v;
  int node = b * 256 + t;
  if (node < N) indptr[node] = base + excl;
  if (b == 0 && t == 0) indptr[N] = E;
  cur[t] = excl;
  __syncthreads();

  for (int i = t; i < sz; i += 256) {
    int d = pd[base + i];
    int slot = atomicAdd(&cur[d & 255], 1);
    u32 gidx = (u32)(base + slot);
    if (gidx < (u32)E) ssrc[gidx] = ps[base + i];
  }
}

// ---------------- B-fragment swizzle buffer ----------------
__global__ __launch_bounds__(256) void bsw_build(const void* __restrict__ W,
                                                 u16* __restrict__ Bsw, int K,
                                                 const int* __restrict__ dflag) {
  const int isbf = dflag[0];
  int t = blockIdx.x * 256 + threadIdx.x;
  int total = (K / 32) * 8 * 64;
  if (t >= total) return;
  int lane = t & 63;
  int c = (t >> 6) & 7;
  int ktile = t >> 9;
  int n = lane & 15, q = lane >> 4;
  int col = c * 16 + n;
  u16 vals[8];
#pragma unroll
  for (int j = 0; j < 8; ++j) {
    int k = ktile * 32 + q * 8 + j;
    int idx = col * K + k;
    vals[j] = isbf ? ((const u16*)W)[idx] : f2bf(((const float*)W)[idx]);
  }
  *(uint4*)(Bsw + (size_t)t * 8) = *(uint4*)vals;
}

// ---------------- MFMA GEMM body: 32 rows/wave (2 row-tiles), 128 rows/block ----
template <int K, int DYNA>
__device__ __forceinline__ void gemm_body(int bix, const void* __restrict__ Xv,
                                          const u16* __restrict__ Bsw,
                                          u16* __restrict__ Hb,
                                          const void* __restrict__ al,
                                          const void* __restrict__ ar,
                                          float* __restrict__ el_,
                                          float* __restrict__ er_, int N,
                                          const int* __restrict__ dflag) {
  const int isbfP = dflag[0];
  const int isbfA = DYNA ? isbfP : 1;  // x intermediate is always bf16
  int tid = threadIdx.x;
  int w = tid >> 6, lane = tid & 63;
  int n = lane & 15, q = lane >> 4;
  int base = bix * 128 + w * 32;  // wave covers rows [base, base+32)

  int mclamp[2];
#pragma unroll
  for (int mt = 0; mt < 2; ++mt) {
    int m = base + mt * 16 + n;
    mclamp[mt] = (m < N) ? m : 0;
  }

  float alv[8], arv[8];
#pragma unroll
  for (int c = 0; c < 8; ++c) {
    alv[c] = loadf(al, c * 16 + n, isbfP);
    arv[c] = loadf(ar, c * 16 + n, isbfP);
  }

  float4v acc[2][8];
#pragma unroll
  for (int mt = 0; mt < 2; ++mt)
#pragma unroll
    for (int c = 0; c < 8; ++c) acc[mt][c] = (float4v){0.f, 0.f, 0.f, 0.f};

#pragma unroll
  for (int t = 0; t < K / 32; ++t) {
    short8 af[2];
#pragma unroll
    for (int mt = 0; mt < 2; ++mt) {
      if (isbfA) {
        af[mt] = *(const short8*)((const u16*)Xv + (size_t)mclamp[mt] * K + t * 32 + q * 8);
      } else {
        const float* Af = (const float*)Xv + (size_t)mclamp[mt] * K + t * 32 + q * 8;
        float4 f0 = *(const float4*)Af;
        float4 f1 = *(const float4*)(Af + 4);
        u16 tmp[8] = {f2bf(f0.x), f2bf(f0.y), f2bf(f0.z), f2bf(f0.w),
                      f2bf(f1.x), f2bf(f1.y), f2bf(f1.z), f2bf(f1.w)};
        af[mt] = *(short8*)tmp;
      }
    }
    const uint4* bt = (const uint4*)Bsw + ((size_t)t * 8) * 64 + lane;
#pragma unroll
    for (int c = 0; c < 8; ++c) {
      uint4 bw = bt[c * 64];
      short8 bf = *(short8*)&bw;
      acc[0][c] = __builtin_amdgcn_mfma_f32_16x16x32_bf16(af[0], bf, acc[0][c], 0, 0, 0);
      acc[1][c] = __builtin_amdgcn_mfma_f32_16x16x32_bf16(af[1], bf, acc[1][c], 0, 0, 0);
    }
  }

  // Hb store: D layout col = c*16 + (lane&15), row = base + mt*16 + q*4 + r
#pragma unroll
  for (int mt = 0; mt < 2; ++mt)
#pragma unroll
    for (int c = 0; c < 8; ++c) {
#pragma unroll
      for (int r = 0; r < 4; ++r) {
        int row = base + mt * 16 + q * 4 + r;
        if (row < N) Hb[(size_t)row * 128 + c * 16 + n] = f2bf(acc[mt][c][r]);
      }
    }

  // fused el/er: reduce across the 16 lanes of each quad-row group
#pragma unroll
  for (int mt = 0; mt < 2; ++mt)
#pragma unroll
    for (int r = 0; r < 4; ++r) {
      float sl = 0.f, sr = 0.f;
#pragma unroll
      for (int c = 0; c < 8; ++c) {
        float v = acc[mt][c][r];
        sl = fmaf(v, alv[c], sl);
        sr = fmaf(v, arv[c], sr);
      }
#pragma unroll
      for (int off = 1; off < 16; off <<= 1) {
        sl += __shfl_xor(sl, off);
        sr += __shfl_xor(sr, off);
      }
      if (n == 0) {
        int row = base + mt * 16 + q * 4 + r;
        if (row < N) {
          el_[row] = sl;
          er_[row] = sr;
        }
      }
    }
}

template <int K, int DYNA>
__global__ __launch_bounds__(256) void gemm_mfma(const void* __restrict__ Xv,
                                                 const u16* __restrict__ Bsw,
                                                 u16* __restrict__ Hb,
                                                 const void* __restrict__ al,
                                                 const void* __restrict__ ar,
                                                 float* __restrict__ el_,
                                                 float* __restrict__ er_, int N,
                                                 const int* __restrict__ dflag) {
  gemm_body<K, DYNA>(blockIdx.x, Xv, Bsw, Hb, al, ar, el_, er_, N, dflag);
}

// fused: blocks [0, gemm_blocks) do GEMM layer 1; the rest do the coarse
// histogram (P1a) of the counting-sort CSR build — LDS atomics only, no
// global atomics anywhere.
template <int K, int DYNA>
__global__ __launch_bounds__(256) void fused_gemm_hist(
    const void* __restrict__ Xv, const u16* __restrict__ Bsw, u16* __restrict__ Hb,
    const void* __restrict__ al, const void* __restrict__ ar,
    float* __restrict__ el_, float* __restrict__ er_, int N,
    const int* __restrict__ dflag, int gemm_blocks,
    const int* __restrict__ dst, int* __restrict__ Gh, int E, int PB, int nbuck) {
  __shared__ int hcnt[MAXBUCK];
  int bix = (int)blockIdx.x;
  if (bix < gemm_blocks) {
    gemm_body<K, DYNA>(bix, Xv, Bsw, Hb, al, ar, el_, er_, N, dflag);
    return;
  }
  int pblk = bix - gemm_blocks;
  int t = threadIdx.x;
  for (int i = t; i < nbuck; i += 256) hcnt[i] = 0;
  __syncthreads();
  int pbase = pblk * 4096;
#pragma unroll
  for (int j = 0; j < 16; ++j) {
    int e = pbase + j * 256 + t;
    if (e < E) {
      u32 b = (u32)dst[e] >> BSHIFT;
      if (b < (u32)nbuck) atomicAdd(&hcnt[b], 1);
    }
  }
  __syncthreads();
  for (int i = t; i < nbuck; i += 256) Gh[(size_t)i * PB + pblk] = hcnt[i];
}

// ---------------- aggregation: two-phase wave-parallel softmax ----------------
template <int MODE>
__global__ __launch_bounds__(256) void agg_kernel(const u32* __restrict__ Hb,
                                                  const float* __restrict__ el,
                                                  const float* __restrict__ er,
                                                  const int* __restrict__ indptr,
                                                  const int* __restrict__ ssrc,
                                                  const void* __restrict__ bias,
                                                  void* __restrict__ outv, int N,
                                                  const int* __restrict__ dflag) {
  const int isbf = dflag[0];
  int tid = threadIdx.x;
  int n = blockIdx.x * 4 + (tid >> 6);
  int lane = tid & 63;
  if (n >= N) return;

  int beg = indptr[n];
  int end = indptr[n + 1];
  float ern = er[n];

  float aa0 = 0.f, aa1 = 0.f;
  float m_run = -INFINITY, l_run = 0.f;

  for (int p = beg; p < end; p += 64) {
    int rem = end - p;  // >= 1
    int valid = lane < rem;
    int ide = valid ? ssrc[p + lane] : 0;

    // lane-parallel scores
    float sc = el[ide] + ern;
    sc = (sc > 0.f) ? sc : NEG_SLOPE * sc;
    sc = valid ? sc : -INFINITY;

    // wave max
    float mc = sc;
#pragma unroll
    for (int off = 1; off < 64; off <<= 1) mc = fmaxf(mc, __shfl_xor(mc, off));

    float m_new = fmaxf(m_run, mc);
    float corr = __expf(m_run - m_new);  // first chunk: exp(-inf)=0
    float pe = __expf(sc - m_new);       // invalid lanes: exp(-inf)=0

    // wave sum of pe
    float ls = pe;
#pragma unroll
    for (int off = 1; off < 64; off <<= 1) ls += __shfl_xor(ls, off);

    l_run = l_run * corr + ls;
    aa0 *= corr;
    aa1 *= corr;
    m_run = m_new;

    // phase 2: gather-accumulate, 4-deep unroll for MLP
    int cl = (rem < 64) ? rem : 64;
    int e = 0;
    for (; e + 4 <= cl; e += 4) {
      int i0 = __builtin_amdgcn_readlane(ide, e);
      int i1 = __builtin_amdgcn_readlane(ide, e + 1);
      int i2 = __builtin_amdgcn_readlane(ide, e + 2);
      int i3 = __builtin_amdgcn_readlane(ide, e + 3);
      u32 h0 = Hb[(size_t)i0 * 64 + lane];
      u32 h1 = Hb[(size_t)i1 * 64 + lane];
      u32 h2 = Hb[(size_t)i2 * 64 + lane];
      u32 h3 = Hb[(size_t)i3 * 64 + lane];
      float p0 = __int_as_float(__builtin_amdgcn_readlane(__float_as_int(pe), e));
      float p1 = __int_as_float(__builtin_amdgcn_readlane(__float_as_int(pe), e + 1));
      float p2 = __int_as_float(__builtin_amdgcn_readlane(__float_as_int(pe), e + 2));
      float p3 = __int_as_float(__builtin_amdgcn_readlane(__float_as_int(pe), e + 3));
      aa0 = fmaf(p0, bflo(h0), aa0);
      aa1 = fmaf(p0, bfhi(h0), aa1);
      aa0 = fmaf(p1, bflo(h1), aa0);
      aa1 = fmaf(p1, bfhi(h1), aa1);
      aa0 = fmaf(p2, bflo(h2), aa0);
      aa1 = fmaf(p2, bfhi(h2), aa1);
      aa0 = fmaf(p3, bflo(h3), aa0);
      aa1 = fmaf(p3, bfhi(h3), aa1);
    }
    for (; e < cl; ++e) {
      int i0 = __builtin_amdgcn_readlane(ide, e);
      u32 h0 = Hb[(size_t)i0 * 64 + lane];
      float p0 = __int_as_float(__builtin_amdgcn_readlane(__float_as_int(pe), e));
      aa0 = fmaf(p0, bflo(h0), aa0);
      aa1 = fmaf(p0, bfhi(h0), aa1);
    }
  }

  float inv = (l_run > 0.f) ? 1.f / l_run : 0.f;
  float o0 = aa0 * inv + loadf(bias, 2 * lane, isbf);
  float o1 = aa1 * inv + loadf(bias, 2 * lane + 1, isbf);

  if (MODE == 0) {
    o0 = (o0 > 0.f) ? o0 : (__expf(o0) - 1.f);
    o1 = (o1 > 0.f) ? o1 : (__expf(o1) - 1.f);
    ((u32*)outv)[(size_t)n * 64 + lane] = (u32)f2bf(o0) | ((u32)f2bf(o1) << 16);
  } else {
    if (isbf) {
      ((u32*)outv)[(size_t)n * 64 + lane] = (u32)f2bf(o0) | ((u32)f2bf(o1) << 16);
    } else {
      ((float2*)outv)[(size_t)n * 64 + lane] = make_float2(o0, o1);
    }
  }
}

// ---------------- launch ----------------

extern "C" void kernel_launch(void* const* d_in, const int* in_sizes, int n_in,
                              void* d_out, int out_size, void* d_ws, size_t ws_size,
                              hipStream_t stream) {
  const int IN_FEATS = 256, HID = 128;
  const void* features = d_in[0];
  const int* src = (const int*)d_in[1];
  const int* dst = (const int*)d_in[2];
  const void* W1 = d_in[3];
  const void* al1 = d_in[4];
  const void* ar1 = d_in[5];
  const void* b1 = d_in[6];
  const void* W2 = d_in[7];
  const void* al2 = d_in[8];
  const void* ar2 = d_in[9];
  const void* b2 = d_in[10];

  const int N = in_sizes[0] / IN_FEATS;  // 100000
  const int E = in_sizes[1];             // 1600000

  char* p = (char*)d_ws;
  auto alloc = [&](size_t bytes) -> void* {
    void* q = (void*)p;
    p += (bytes + 255) & ~(size_t)255;
    return q;
  };
  int* dflag = (int*)alloc(256);
  u16* Bsw1 = (u16*)alloc((size_t)(IN_FEATS / 32) * 8 * 64 * 8 * 2);  // 64 KB
  u16* Bsw2 = (u16*)alloc((size_t)(HID / 32) * 8 * 64 * 8 * 2);       // 32 KB
  u16* hb = (u16*)alloc((size_t)N * HID * 2);  // 25.6 MB
  u16* x = (u16*)alloc((size_t)N * HID * 2);   // 25.6 MB
  float* el = (float*)alloc((size_t)N * 4);
  float* er = (float*)alloc((size_t)N * 4);
  int* indptr = (int*)alloc((size_t)(N + 1) * 4);

  const int nbuck = (N + 255) >> BSHIFT;  // 391
  const int PB = (E + 4095) / 4096;       // 391 (4096 edges per P1 block)
  const int M = nbuck * PB;               // 152881
  const int MB1 = (M + 255) / 256;        // 598

  int* Gh = (int*)alloc((size_t)M * 4);       // 0.6 MB
  int* bsumA = (int*)alloc((size_t)MB1 * 4);  // 2.4 KB
  int* ssrc = (int*)alloc((size_t)E * 4);     // 6.4 MB

  // pd/ps ALIAS the x buffer (workspace safety): pd/ps are dead after
  // bucket_sort completes; x is first written by agg_kernel<0>, which is
  // stream-ordered strictly after bucket_sort. 2*E*4 = 12.8 MB < 25.6 MB.
  int* pd = (int*)x;
  int* ps = (int*)((char*)x + (((size_t)E * 4 + 255) & ~(size_t)255));

  const int GEMM_B = (N + 127) / 128;  // 782 (128 rows/block)
  const int NODE_B = (N + 3) / 4;      // 25000

  detect_dtype<<<1, 256, 0, stream>>>((const u32*)features, 4096, dflag);
  bsw_build<<<((IN_FEATS / 32) * 8 * 64 + 255) / 256, 256, 0, stream>>>(W1, Bsw1, IN_FEATS, dflag);
  bsw_build<<<((HID / 32) * 8 * 64 + 255) / 256, 256, 0, stream>>>(W2, Bsw2, HID, dflag);

  // GEMM layer 1 (+ fused el/er) co-scheduled with the coarse histogram
  fused_gemm_hist<IN_FEATS, 1><<<GEMM_B + PB, 256, 0, stream>>>(
      features, Bsw1, hb, al1, ar1, el, er, N, dflag, GEMM_B, dst, Gh, E, PB, nbuck);

  // scan Gh (bucket-major) -> global partition offsets
  scanA<<<MB1, 256, 0, stream>>>(Gh, bsumA, M);
  scanBseq<<<1, 512, 0, stream>>>(bsumA, MB1);
  scanC<<<MB1, 256, 0, stream>>>(Gh, bsumA, M);

  // partition edges into coarse-bucket-major order, then fine-sort per bucket
  part_scatter<<<PB, 256, 0, stream>>>(src, dst, Gh, pd, ps, E, PB, nbuck);
  bucket_sort<<<nbuck, 256, 0, stream>>>(pd, ps, Gh, indptr, ssrc, E, N, PB, nbuck);

  agg_kernel<0><<<NODE_B, 256, 0, stream>>>((const u32*)hb, el, er, indptr, ssrc, b1, (void*)x, N, dflag);

  gemm_mfma<HID, 0><<<GEMM_B, 256, 0, stream>>>((const void*)x, Bsw2, hb, al2, ar2, el, er, N, dflag);
  agg_kernel<1><<<NODE_B, 256, 0, stream>>>((const u32*)hb, el, er, indptr, ssrc, b2, d_out, N, dflag);
}

// Round 8
// 468.668 us; speedup vs baseline: 1.0564x; 1.0264x over previous
//
#include <hip/hip_runtime.h>

typedef unsigned short u16;
typedef unsigned int u32;

#define NEG_SLOPE 0.2f
#define BSHIFT 8
#define MAXBUCK 1024  // supports N up to 262144

using short8 = __attribute__((ext_vector_type(8))) short;
using float4v = __attribute__((ext_vector_type(4))) float;

__device__ __forceinline__ float bfu(u16 v) { return __uint_as_float(((u32)v) << 16); }
__device__ __forceinline__ float bflo(u32 u) { return __uint_as_float(u << 16); }
__device__ __forceinline__ float bfhi(u32 u) { return __uint_as_float(u & 0xffff0000u); }
__device__ __forceinline__ u16 f2bf(float f) {
  u32 x = __float_as_uint(f);
  return (u16)((x + 0x7fffu + ((x >> 16) & 1u)) >> 16);
}
__device__ __forceinline__ float loadf(const void* p, int idx, int isbf) {
  return isbf ? bfu(((const u16*)p)[idx]) : ((const float*)p)[idx];
}

// ---------------- dtype detection (bf16 vs f32 inputs) ----------------
__global__ __launch_bounds__(256) void detect_dtype(const u32* __restrict__ w,
                                                    int nwords, int* __restrict__ flag) {
  __shared__ int cnt;
  if (threadIdx.x == 0) cnt = 0;
  __syncthreads();
  int c = 0;
  for (int i = threadIdx.x; i < nwords; i += 256) {
    u32 e = (w[i] >> 7) & 0xFFu;  // exponent of low-half-as-bf16
    c += (e >= 0x60u && e <= 0x90u) ? 1 : 0;
  }
  atomicAdd(&cnt, c);
  __syncthreads();
  if (threadIdx.x == 0) flag[0] = (cnt * 2 > nwords) ? 1 : 0;  // 1 = bf16
}

// ---------------- generic scan kernels (for Gh, M up to ~160K) ----------------
__global__ __launch_bounds__(256) void scanA(int* __restrict__ a,
                                             int* __restrict__ bsum, int M) {
  __shared__ int sh[256];
  int t = threadIdx.x;
  int idx = blockIdx.x * 256 + t;
  int v = (idx < M) ? a[idx] : 0;
  sh[t] = v;
  __syncthreads();
  for (int off = 1; off < 256; off <<= 1) {
    int y = (t >= off) ? sh[t - off] : 0;
    __syncthreads();
    sh[t] += y;
    __syncthreads();
  }
  if (idx < M) a[idx] = sh[t] - v;  // exclusive, pre-offset
  if (t == 255) bsum[blockIdx.x] = sh[255];
}

// single-block sequential-chunk exclusive scan (any MB)
__global__ __launch_bounds__(512) void scanBseq(int* __restrict__ a, int MB) {
  __shared__ int sh[512];
  __shared__ int carry;
  int t = threadIdx.x;
  if (t == 0) carry = 0;
  __syncthreads();
  for (int base = 0; base < MB; base += 512) {
    int v = (base + t < MB) ? a[base + t] : 0;
    sh[t] = v;
    __syncthreads();
    for (int off = 1; off < 512; off <<= 1) {
      int y = (t >= off) ? sh[t - off] : 0;
      __syncthreads();
      sh[t] += y;
      __syncthreads();
    }
    int c0 = carry;
    int excl = sh[t] - v + c0;
    int tot = sh[511];
    __syncthreads();
    if (t == 0) carry = c0 + tot;
    if (base + t < MB) a[base + t] = excl;
    __syncthreads();
  }
}

__global__ __launch_bounds__(256) void scanC(int* __restrict__ a,
                                             const int* __restrict__ boff, int M) {
  int idx = blockIdx.x * 256 + threadIdx.x;
  if (idx < M) a[idx] += boff[blockIdx.x];
}

// ---------------- P1c: partition (dst,src) into coarse-bucket-major order -------
__global__ __launch_bounds__(256) void part_scatter(const int* __restrict__ src,
                                                    const int* __restrict__ dst,
                                                    const int* __restrict__ Gh,
                                                    int* __restrict__ pd,
                                                    int* __restrict__ ps,
                                                    int E, int PB, int nbuck) {
  __shared__ int cur[MAXBUCK];
  int t = threadIdx.x;
  int blk = blockIdx.x;
  for (int i = t; i < nbuck; i += 256) cur[i] = Gh[(size_t)i * PB + blk];
  __syncthreads();
  int pbase = blk * 4096;
#pragma unroll
  for (int j = 0; j < 16; ++j) {
    int e = pbase + j * 256 + t;
    if (e < E) {
      int d = dst[e];
      int s = src[e];
      u32 b = (u32)d >> BSHIFT;
      if (b < (u32)nbuck) {
        int slot = atomicAdd(&cur[b], 1);
        if ((u32)slot < (u32)E) {
          pd[slot] = d;
          ps[slot] = s;
        }
      }
    }
  }
}

// ---------------- P2: per-bucket fine counting sort + indptr ----------------
__global__ __launch_bounds__(256) void bucket_sort(const int* __restrict__ pd,
                                                   const int* __restrict__ ps,
                                                   const int* __restrict__ Gh,
                                                   int* __restrict__ indptr,
                                                   int* __restrict__ ssrc,
                                                   int E, int N, int PB, int nbuck) {
  __shared__ int bins[256];
  __shared__ int sh[256];
  __shared__ int cur[256];
  int t = threadIdx.x;
  int b = blockIdx.x;
  int base = Gh[(size_t)b * PB];
  int nextb = (b + 1 < nbuck) ? Gh[(size_t)(b + 1) * PB] : E;
  int sz = nextb - base;

  bins[t] = 0;
  __syncthreads();
  for (int i = t; i < sz; i += 256) atomicAdd(&bins[pd[base + i] & 255], 1);
  __syncthreads();

  int v = bins[t];
  sh[t] = v;
  __syncthreads();
  for (int off = 1; off < 256; off <<= 1) {
    int y = (t >= off) ? sh[t - off] : 0;
    __syncthreads();
    sh[t] += y;
    __syncthreads();
  }
  int excl = sh[t] - v;
  int node = b * 256 + t;
  if (node < N) indptr[node] = base + excl;
  if (b == 0 && t == 0) indptr[N] = E;
  cur[t] = excl;
  __syncthreads();

  for (int i = t; i < sz; i += 256) {
    int d = pd[base + i];
    int slot = atomicAdd(&cur[d & 255], 1);
    u32 gidx = (u32)(base + slot);
    if (gidx < (u32)E) ssrc[gidx] = ps[base + i];
  }
}

// ---------------- B-fragment swizzle buffer ----------------
__global__ __launch_bounds__(256) void bsw_build(const void* __restrict__ W,
                                                 u16* __restrict__ Bsw, int K,
                                                 const int* __restrict__ dflag) {
  const int isbf = dflag[0];
  int t = blockIdx.x * 256 + threadIdx.x;
  int total = (K / 32) * 8 * 64;
  if (t >= total) return;
  int lane = t & 63;
  int c = (t >> 6) & 7;
  int ktile = t >> 9;
  int n = lane & 15, q = lane >> 4;
  int col = c * 16 + n;
  u16 vals[8];
#pragma unroll
  for (int j = 0; j < 8; ++j) {
    int k = ktile * 32 + q * 8 + j;
    int idx = col * K + k;
    vals[j] = isbf ? ((const u16*)W)[idx] : f2bf(((const float*)W)[idx]);
  }
  *(uint4*)(Bsw + (size_t)t * 8) = *(uint4*)vals;
}

// ---------------- MFMA GEMM core: branch-free specialized k-loop ----------------
// r8: dtype branch lifted OUT of the k-loop (template ISBF, selected once at
// entry) so the scheduler can software-pipeline; explicit depth-2 A-prefetch:
// tile t+1's A operands are issued before tile t's 16 MFMAs.
template <int K, int ISBF>
__device__ __forceinline__ void gemm_core(const void* __restrict__ Xv,
                                          const u16* __restrict__ Bsw,
                                          const int* mclamp, int q, int lane,
                                          float4v acc[2][8]) {
  constexpr int NT = K / 32;
  const uint4* btb = (const uint4*)Bsw + lane;
  if (ISBF) {
    const u16* X0 = (const u16*)Xv + (size_t)mclamp[0] * K + q * 8;
    const u16* X1 = (const u16*)Xv + (size_t)mclamp[1] * K + q * 8;
    short8 a0 = *(const short8*)X0;
    short8 a1 = *(const short8*)X1;
#pragma unroll
    for (int t = 0; t < NT; ++t) {
      short8 n0 = a0, n1 = a1;
      if (t + 1 < NT) {
        n0 = *(const short8*)(X0 + (t + 1) * 32);
        n1 = *(const short8*)(X1 + (t + 1) * 32);
      }
      const uint4* bt = btb + (size_t)t * 8 * 64;
#pragma unroll
      for (int c = 0; c < 8; ++c) {
        uint4 bw = bt[c * 64];
        short8 bf = *(short8*)&bw;
        acc[0][c] = __builtin_amdgcn_mfma_f32_16x16x32_bf16(a0, bf, acc[0][c], 0, 0, 0);
        acc[1][c] = __builtin_amdgcn_mfma_f32_16x16x32_bf16(a1, bf, acc[1][c], 0, 0, 0);
      }
      a0 = n0;
      a1 = n1;
    }
  } else {
    const float* X0 = (const float*)Xv + (size_t)mclamp[0] * K + q * 8;
    const float* X1 = (const float*)Xv + (size_t)mclamp[1] * K + q * 8;
    float4 f00 = *(const float4*)X0, f01 = *(const float4*)(X0 + 4);
    float4 f10 = *(const float4*)X1, f11 = *(const float4*)(X1 + 4);
#pragma unroll
    for (int t = 0; t < NT; ++t) {
      float4 g00 = f00, g01 = f01, g10 = f10, g11 = f11;
      if (t + 1 < NT) {
        g00 = *(const float4*)(X0 + (t + 1) * 32);
        g01 = *(const float4*)(X0 + (t + 1) * 32 + 4);
        g10 = *(const float4*)(X1 + (t + 1) * 32);
        g11 = *(const float4*)(X1 + (t + 1) * 32 + 4);
      }
      u16 t0[8] = {f2bf(f00.x), f2bf(f00.y), f2bf(f00.z), f2bf(f00.w),
                   f2bf(f01.x), f2bf(f01.y), f2bf(f01.z), f2bf(f01.w)};
      u16 t1[8] = {f2bf(f10.x), f2bf(f10.y), f2bf(f10.z), f2bf(f10.w),
                   f2bf(f11.x), f2bf(f11.y), f2bf(f11.z), f2bf(f11.w)};
      short8 a0 = *(short8*)t0;
      short8 a1 = *(short8*)t1;
      const uint4* bt = btb + (size_t)t * 8 * 64;
#pragma unroll
      for (int c = 0; c < 8; ++c) {
        uint4 bw = bt[c * 64];
        short8 bf = *(short8*)&bw;
        acc[0][c] = __builtin_amdgcn_mfma_f32_16x16x32_bf16(a0, bf, acc[0][c], 0, 0, 0);
        acc[1][c] = __builtin_amdgcn_mfma_f32_16x16x32_bf16(a1, bf, acc[1][c], 0, 0, 0);
      }
      f00 = g00; f01 = g01; f10 = g10; f11 = g11;
    }
  }
}

// ---------------- MFMA GEMM body: 32 rows/wave (2 row-tiles), 128 rows/block ----
template <int K, int DYNA>
__device__ __forceinline__ void gemm_body(int bix, const void* __restrict__ Xv,
                                          const u16* __restrict__ Bsw,
                                          u16* __restrict__ Hb,
                                          const void* __restrict__ al,
                                          const void* __restrict__ ar,
                                          float* __restrict__ el_,
                                          float* __restrict__ er_, int N,
                                          const int* __restrict__ dflag) {
  const int isbfP = dflag[0];
  int tid = threadIdx.x;
  int w = tid >> 6, lane = tid & 63;
  int n = lane & 15, q = lane >> 4;
  int base = bix * 128 + w * 32;  // wave covers rows [base, base+32)

  int mclamp[2];
#pragma unroll
  for (int mt = 0; mt < 2; ++mt) {
    int m = base + mt * 16 + n;
    mclamp[mt] = (m < N) ? m : 0;
  }

  float alv[8], arv[8];
#pragma unroll
  for (int c = 0; c < 8; ++c) {
    alv[c] = loadf(al, c * 16 + n, isbfP);
    arv[c] = loadf(ar, c * 16 + n, isbfP);
  }

  float4v acc[2][8];
#pragma unroll
  for (int mt = 0; mt < 2; ++mt)
#pragma unroll
    for (int c = 0; c < 8; ++c) acc[mt][c] = (float4v){0.f, 0.f, 0.f, 0.f};

  // x intermediate is always bf16; features dtype is runtime (dflag).
  if (DYNA == 0 || isbfP) {
    gemm_core<K, 1>(Xv, Bsw, mclamp, q, lane, acc);
  } else {
    gemm_core<K, 0>(Xv, Bsw, mclamp, q, lane, acc);
  }

  // Hb store: D layout col = c*16 + (lane&15), row = base + mt*16 + q*4 + r
#pragma unroll
  for (int mt = 0; mt < 2; ++mt)
#pragma unroll
    for (int c = 0; c < 8; ++c) {
#pragma unroll
      for (int r = 0; r < 4; ++r) {
        int row = base + mt * 16 + q * 4 + r;
        if (row < N) Hb[(size_t)row * 128 + c * 16 + n] = f2bf(acc[mt][c][r]);
      }
    }

  // fused el/er: reduce across the 16 lanes of each quad-row group
#pragma unroll
  for (int mt = 0; mt < 2; ++mt)
#pragma unroll
    for (int r = 0; r < 4; ++r) {
      float sl = 0.f, sr = 0.f;
#pragma unroll
      for (int c = 0; c < 8; ++c) {
        float v = acc[mt][c][r];
        sl = fmaf(v, alv[c], sl);
        sr = fmaf(v, arv[c], sr);
      }
#pragma unroll
      for (int off = 1; off < 16; off <<= 1) {
        sl += __shfl_xor(sl, off);
        sr += __shfl_xor(sr, off);
      }
      if (n == 0) {
        int row = base + mt * 16 + q * 4 + r;
        if (row < N) {
          el_[row] = sl;
          er_[row] = sr;
        }
      }
    }
}

template <int K, int DYNA>
__global__ __launch_bounds__(256) void gemm_mfma(const void* __restrict__ Xv,
                                                 const u16* __restrict__ Bsw,
                                                 u16* __restrict__ Hb,
                                                 const void* __restrict__ al,
                                                 const void* __restrict__ ar,
                                                 float* __restrict__ el_,
                                                 float* __restrict__ er_, int N,
                                                 const int* __restrict__ dflag) {
  gemm_body<K, DYNA>(blockIdx.x, Xv, Bsw, Hb, al, ar, el_, er_, N, dflag);
}

// fused: blocks [0, gemm_blocks) do GEMM layer 1; the rest do the coarse
// histogram (P1a) of the counting-sort CSR build — LDS atomics only.
template <int K, int DYNA>
__global__ __launch_bounds__(256) void fused_gemm_hist(
    const void* __restrict__ Xv, const u16* __restrict__ Bsw, u16* __restrict__ Hb,
    const void* __restrict__ al, const void* __restrict__ ar,
    float* __restrict__ el_, float* __restrict__ er_, int N,
    const int* __restrict__ dflag, int gemm_blocks,
    const int* __restrict__ dst, int* __restrict__ Gh, int E, int PB, int nbuck) {
  __shared__ int hcnt[MAXBUCK];
  int bix = (int)blockIdx.x;
  if (bix < gemm_blocks) {
    gemm_body<K, DYNA>(bix, Xv, Bsw, Hb, al, ar, el_, er_, N, dflag);
    return;
  }
  int pblk = bix - gemm_blocks;
  int t = threadIdx.x;
  for (int i = t; i < nbuck; i += 256) hcnt[i] = 0;
  __syncthreads();
  int pbase = pblk * 4096;
#pragma unroll
  for (int j = 0; j < 16; ++j) {
    int e = pbase + j * 256 + t;
    if (e < E) {
      u32 b = (u32)dst[e] >> BSHIFT;
      if (b < (u32)nbuck) atomicAdd(&hcnt[b], 1);
    }
  }
  __syncthreads();
  for (int i = t; i < nbuck; i += 256) Gh[(size_t)i * PB + pblk] = hcnt[i];
}

// ---------------- aggregation: two-phase wave-parallel softmax ----------------
// r8: phase-2 gather deepened to 8 outstanding Hb loads per wave.
template <int MODE>
__global__ __launch_bounds__(256) void agg_kernel(const u32* __restrict__ Hb,
                                                  const float* __restrict__ el,
                                                  const float* __restrict__ er,
                                                  const int* __restrict__ indptr,
                                                  const int* __restrict__ ssrc,
                                                  const void* __restrict__ bias,
                                                  void* __restrict__ outv, int N,
                                                  const int* __restrict__ dflag) {
  const int isbf = dflag[0];
  int tid = threadIdx.x;
  int n = blockIdx.x * 4 + (tid >> 6);
  int lane = tid & 63;
  if (n >= N) return;

  int beg = indptr[n];
  int end = indptr[n + 1];
  float ern = er[n];

  float aa0 = 0.f, aa1 = 0.f;
  float m_run = -INFINITY, l_run = 0.f;

  for (int p = beg; p < end; p += 64) {
    int rem = end - p;  // >= 1
    int valid = lane < rem;
    int ide = valid ? ssrc[p + lane] : 0;

    // lane-parallel scores
    float sc = el[ide] + ern;
    sc = (sc > 0.f) ? sc : NEG_SLOPE * sc;
    sc = valid ? sc : -INFINITY;

    // wave max
    float mc = sc;
#pragma unroll
    for (int off = 1; off < 64; off <<= 1) mc = fmaxf(mc, __shfl_xor(mc, off));

    float m_new = fmaxf(m_run, mc);
    float corr = __expf(m_run - m_new);  // first chunk: exp(-inf)=0
    float pe = __expf(sc - m_new);       // invalid lanes: exp(-inf)=0

    // wave sum of pe
    float ls = pe;
#pragma unroll
    for (int off = 1; off < 64; off <<= 1) ls += __shfl_xor(ls, off);

    l_run = l_run * corr + ls;
    aa0 *= corr;
    aa1 *= corr;
    m_run = m_new;

    // phase 2: gather-accumulate, 8-deep for MLP
    int cl = (rem < 64) ? rem : 64;
    int e = 0;
    for (; e + 8 <= cl; e += 8) {
      int id_[8];
      u32 h_[8];
#pragma unroll
      for (int k = 0; k < 8; ++k) id_[k] = __builtin_amdgcn_readlane(ide, e + k);
#pragma unroll
      for (int k = 0; k < 8; ++k) h_[k] = Hb[(size_t)id_[k] * 64 + lane];
#pragma unroll
      for (int k = 0; k < 8; ++k) {
        float pk = __int_as_float(__builtin_amdgcn_readlane(__float_as_int(pe), e + k));
        aa0 = fmaf(pk, bflo(h_[k]), aa0);
        aa1 = fmaf(pk, bfhi(h_[k]), aa1);
      }
    }
    for (; e + 4 <= cl; e += 4) {
      int id_[4];
      u32 h_[4];
#pragma unroll
      for (int k = 0; k < 4; ++k) id_[k] = __builtin_amdgcn_readlane(ide, e + k);
#pragma unroll
      for (int k = 0; k < 4; ++k) h_[k] = Hb[(size_t)id_[k] * 64 + lane];
#pragma unroll
      for (int k = 0; k < 4; ++k) {
        float pk = __int_as_float(__builtin_amdgcn_readlane(__float_as_int(pe), e + k));
        aa0 = fmaf(pk, bflo(h_[k]), aa0);
        aa1 = fmaf(pk, bfhi(h_[k]), aa1);
      }
    }
    for (; e < cl; ++e) {
      int i0 = __builtin_amdgcn_readlane(ide, e);
      u32 h0 = Hb[(size_t)i0 * 64 + lane];
      float p0 = __int_as_float(__builtin_amdgcn_readlane(__float_as_int(pe), e));
      aa0 = fmaf(p0, bflo(h0), aa0);
      aa1 = fmaf(p0, bfhi(h0), aa1);
    }
  }

  float inv = (l_run > 0.f) ? 1.f / l_run : 0.f;
  float o0 = aa0 * inv + loadf(bias, 2 * lane, isbf);
  float o1 = aa1 * inv + loadf(bias, 2 * lane + 1, isbf);

  if (MODE == 0) {
    o0 = (o0 > 0.f) ? o0 : (__expf(o0) - 1.f);
    o1 = (o1 > 0.f) ? o1 : (__expf(o1) - 1.f);
    ((u32*)outv)[(size_t)n * 64 + lane] = (u32)f2bf(o0) | ((u32)f2bf(o1) << 16);
  } else {
    if (isbf) {
      ((u32*)outv)[(size_t)n * 64 + lane] = (u32)f2bf(o0) | ((u32)f2bf(o1) << 16);
    } else {
      ((float2*)outv)[(size_t)n * 64 + lane] = make_float2(o0, o1);
    }
  }
}

// ---------------- launch ----------------

extern "C" void kernel_launch(void* const* d_in, const int* in_sizes, int n_in,
                              void* d_out, int out_size, void* d_ws, size_t ws_size,
                              hipStream_t stream) {
  const int IN_FEATS = 256, HID = 128;
  const void* features = d_in[0];
  const int* src = (const int*)d_in[1];
  const int* dst = (const int*)d_in[2];
  const void* W1 = d_in[3];
  const void* al1 = d_in[4];
  const void* ar1 = d_in[5];
  const void* b1 = d_in[6];
  const void* W2 = d_in[7];
  const void* al2 = d_in[8];
  const void* ar2 = d_in[9];
  const void* b2 = d_in[10];

  const int N = in_sizes[0] / IN_FEATS;  // 100000
  const int E = in_sizes[1];             // 1600000

  char* p = (char*)d_ws;
  auto alloc = [&](size_t bytes) -> void* {
    void* q = (void*)p;
    p += (bytes + 255) & ~(size_t)255;
    return q;
  };
  int* dflag = (int*)alloc(256);
  u16* Bsw1 = (u16*)alloc((size_t)(IN_FEATS / 32) * 8 * 64 * 8 * 2);  // 64 KB
  u16* Bsw2 = (u16*)alloc((size_t)(HID / 32) * 8 * 64 * 8 * 2);       // 32 KB
  u16* hb = (u16*)alloc((size_t)N * HID * 2);  // 25.6 MB
  u16* x = (u16*)alloc((size_t)N * HID * 2);   // 25.6 MB
  float* el = (float*)alloc((size_t)N * 4);
  float* er = (float*)alloc((size_t)N * 4);
  int* indptr = (int*)alloc((size_t)(N + 1) * 4);

  const int nbuck = (N + 255) >> BSHIFT;  // 391
  const int PB = (E + 4095) / 4096;       // 391 (4096 edges per P1 block)
  const int M = nbuck * PB;               // 152881
  const int MB1 = (M + 255) / 256;        // 598

  int* Gh = (int*)alloc((size_t)M * 4);       // 0.6 MB
  int* bsumA = (int*)alloc((size_t)MB1 * 4);  // 2.4 KB
  int* ssrc = (int*)alloc((size_t)E * 4);     // 6.4 MB

  // pd/ps ALIAS the x buffer (workspace safety): pd/ps are dead after
  // bucket_sort completes; x is first written by agg_kernel<0>, which is
  // stream-ordered strictly after bucket_sort. 2*E*4 = 12.8 MB < 25.6 MB.
  int* pd = (int*)x;
  int* ps = (int*)((char*)x + (((size_t)E * 4 + 255) & ~(size_t)255));

  const int GEMM_B = (N + 127) / 128;  // 782 (128 rows/block)
  const int NODE_B = (N + 3) / 4;      // 25000

  detect_dtype<<<1, 256, 0, stream>>>((const u32*)features, 4096, dflag);
  bsw_build<<<((IN_FEATS / 32) * 8 * 64 + 255) / 256, 256, 0, stream>>>(W1, Bsw1, IN_FEATS, dflag);
  bsw_build<<<((HID / 32) * 8 * 64 + 255) / 256, 256, 0, stream>>>(W2, Bsw2, HID, dflag);

  // GEMM layer 1 (+ fused el/er) co-scheduled with the coarse histogram
  fused_gemm_hist<IN_FEATS, 1><<<GEMM_B + PB, 256, 0, stream>>>(
      features, Bsw1, hb, al1, ar1, el, er, N, dflag, GEMM_B, dst, Gh, E, PB, nbuck);

  // scan Gh (bucket-major) -> global partition offsets
  scanA<<<MB1, 256, 0, stream>>>(Gh, bsumA, M);
  scanBseq<<<1, 512, 0, stream>>>(bsumA, MB1);
  scanC<<<MB1, 256, 0, stream>>>(Gh, bsumA, M);

  // partition edges into coarse-bucket-major order, then fine-sort per bucket
  part_scatter<<<PB, 256, 0, stream>>>(src, dst, Gh, pd, ps, E, PB, nbuck);
  bucket_sort<<<nbuck, 256, 0, stream>>>(pd, ps, Gh, indptr, ssrc, E, N, PB, nbuck);

  agg_kernel<0><<<NODE_B, 256, 0, stream>>>((const u32*)hb, el, er, indptr, ssrc, b1, (void*)x, N, dflag);

  gemm_mfma<HID, 0><<<GEMM_B, 256, 0, stream>>>((const void*)x, Bsw2, hb, al2, ar2, el, er, N, dflag);
  agg_kernel<1><<<NODE_B, 256, 0, stream>>>((const u32*)hb, el, er, indptr, ssrc, b2, d_out, N, dflag);
}

// Round 9
// 452.903 us; speedup vs baseline: 1.0931x; 1.0348x over previous
//
#include <hip/hip_runtime.h>

typedef unsigned short u16;
typedef unsigned int u32;

#define NEG_SLOPE 0.2f
#define BSHIFT 8
#define MAXBUCK 1024  // supports N up to 262144

using short8 = __attribute__((ext_vector_type(8))) short;
using float4v = __attribute__((ext_vector_type(4))) float;
using float2v = __attribute__((ext_vector_type(2))) float;

__device__ __forceinline__ float bfu(u16 v) { return __uint_as_float(((u32)v) << 16); }
__device__ __forceinline__ float bflo(u32 u) { return __uint_as_float(u << 16); }
__device__ __forceinline__ float bfhi(u32 u) { return __uint_as_float(u & 0xffff0000u); }
__device__ __forceinline__ u16 f2bf(float f) {
  u32 x = __float_as_uint(f);
  return (u16)((x + 0x7fffu + ((x >> 16) & 1u)) >> 16);
}
__device__ __forceinline__ float loadf(const void* p, int idx, int isbf) {
  return isbf ? bfu(((const u16*)p)[idx]) : ((const float*)p)[idx];
}

// ---------------- dtype detection (bf16 vs f32 inputs) ----------------
__global__ __launch_bounds__(256) void detect_dtype(const u32* __restrict__ w,
                                                    int nwords, int* __restrict__ flag) {
  __shared__ int cnt;
  if (threadIdx.x == 0) cnt = 0;
  __syncthreads();
  int c = 0;
  for (int i = threadIdx.x; i < nwords; i += 256) {
    u32 e = (w[i] >> 7) & 0xFFu;  // exponent of low-half-as-bf16
    c += (e >= 0x60u && e <= 0x90u) ? 1 : 0;
  }
  atomicAdd(&cnt, c);
  __syncthreads();
  if (threadIdx.x == 0) flag[0] = (cnt * 2 > nwords) ? 1 : 0;  // 1 = bf16
}

// ---------------- generic scan kernels (for Gh, M up to ~160K) ----------------
__global__ __launch_bounds__(256) void scanA(int* __restrict__ a,
                                             int* __restrict__ bsum, int M) {
  __shared__ int sh[256];
  int t = threadIdx.x;
  int idx = blockIdx.x * 256 + t;
  int v = (idx < M) ? a[idx] : 0;
  sh[t] = v;
  __syncthreads();
  for (int off = 1; off < 256; off <<= 1) {
    int y = (t >= off) ? sh[t - off] : 0;
    __syncthreads();
    sh[t] += y;
    __syncthreads();
  }
  if (idx < M) a[idx] = sh[t] - v;  // exclusive, pre-offset (boff applied by consumers)
  if (t == 255) bsum[blockIdx.x] = sh[255];
}

// single-block sequential-chunk exclusive scan (any MB)
__global__ __launch_bounds__(512) void scanBseq(int* __restrict__ a, int MB) {
  __shared__ int sh[512];
  __shared__ int carry;
  int t = threadIdx.x;
  if (t == 0) carry = 0;
  __syncthreads();
  for (int base = 0; base < MB; base += 512) {
    int v = (base + t < MB) ? a[base + t] : 0;
    sh[t] = v;
    __syncthreads();
    for (int off = 1; off < 512; off <<= 1) {
      int y = (t >= off) ? sh[t - off] : 0;
      __syncthreads();
      sh[t] += y;
      __syncthreads();
    }
    int c0 = carry;
    int excl = sh[t] - v + c0;
    int tot = sh[511];
    __syncthreads();
    if (t == 0) carry = c0 + tot;
    if (base + t < MB) a[base + t] = excl;
    __syncthreads();
  }
}

// ---------------- P1c: partition (dst,src) into coarse-bucket-major order -------
// Final offset = Gh[j] (per-256-block exclusive) + bsumA[j>>8] (block offset) —
// scanC folded in here (r9).
__global__ __launch_bounds__(256) void part_scatter(const int* __restrict__ src,
                                                    const int* __restrict__ dst,
                                                    const int* __restrict__ Gh,
                                                    const int* __restrict__ bsumA,
                                                    int* __restrict__ pd,
                                                    int* __restrict__ ps,
                                                    int E, int PB, int nbuck) {
  __shared__ int cur[MAXBUCK];
  int t = threadIdx.x;
  int blk = blockIdx.x;
  for (int i = t; i < nbuck; i += 256) {
    int j = i * PB + blk;
    cur[i] = Gh[j] + bsumA[j >> 8];
  }
  __syncthreads();
  int pbase = blk * 4096;
#pragma unroll
  for (int j = 0; j < 16; ++j) {
    int e = pbase + j * 256 + t;
    if (e < E) {
      int d = dst[e];
      int s = src[e];
      u32 b = (u32)d >> BSHIFT;
      if (b < (u32)nbuck) {
        int slot = atomicAdd(&cur[b], 1);
        if ((u32)slot < (u32)E) {
          pd[slot] = d;
          ps[slot] = s;
        }
      }
    }
  }
}

// ---------------- P2: per-bucket fine counting sort + indptr ----------------
__global__ __launch_bounds__(256) void bucket_sort(const int* __restrict__ pd,
                                                   const int* __restrict__ ps,
                                                   const int* __restrict__ Gh,
                                                   const int* __restrict__ bsumA,
                                                   int* __restrict__ indptr,
                                                   int* __restrict__ ssrc,
                                                   int E, int N, int PB, int nbuck) {
  __shared__ int bins[256];
  __shared__ int sh[256];
  __shared__ int cur[256];
  int t = threadIdx.x;
  int b = blockIdx.x;
  int j0 = b * PB;
  int base = Gh[j0] + bsumA[j0 >> 8];
  int nextb = E;
  if (b + 1 < nbuck) {
    int j1 = (b + 1) * PB;
    nextb = Gh[j1] + bsumA[j1 >> 8];
  }
  int sz = nextb - base;

  bins[t] = 0;
  __syncthreads();
  for (int i = t; i < sz; i += 256) atomicAdd(&bins[pd[base + i] & 255], 1);
  __syncthreads();

  int v = bins[t];
  sh[t] = v;
  __syncthreads();
  for (int off = 1; off < 256; off <<= 1) {
    int y = (t >= off) ? sh[t - off] : 0;
    __syncthreads();
    sh[t] += y;
    __syncthreads();
  }
  int excl = sh[t] - v;
  int node = b * 256 + t;
  if (node < N) indptr[node] = base + excl;
  if (b == 0 && t == 0) indptr[N] = E;
  cur[t] = excl;
  __syncthreads();

  for (int i = t; i < sz; i += 256) {
    int d = pd[base + i];
    int slot = atomicAdd(&cur[d & 255], 1);
    u32 gidx = (u32)(base + slot);
    if (gidx < (u32)E) ssrc[gidx] = ps[base + i];
  }
}

// ---------------- B-fragment swizzle buffer ----------------
__global__ __launch_bounds__(256) void bsw_build(const void* __restrict__ W,
                                                 u16* __restrict__ Bsw, int K,
                                                 const int* __restrict__ dflag) {
  const int isbf = dflag[0];
  int t = blockIdx.x * 256 + threadIdx.x;
  int total = (K / 32) * 8 * 64;
  if (t >= total) return;
  int lane = t & 63;
  int c = (t >> 6) & 7;
  int ktile = t >> 9;
  int n = lane & 15, q = lane >> 4;
  int col = c * 16 + n;
  u16 vals[8];
#pragma unroll
  for (int j = 0; j < 8; ++j) {
    int k = ktile * 32 + q * 8 + j;
    int idx = col * K + k;
    vals[j] = isbf ? ((const u16*)W)[idx] : f2bf(((const float*)W)[idx]);
  }
  *(uint4*)(Bsw + (size_t)t * 8) = *(uint4*)vals;
}

// ---------------- B staging: global -> LDS via global_load_lds (width 16) -------
// Linear copy: LDS dest is wave-uniform base (HW adds lane*16); global source is
// per-lane. Compiler never auto-emits this (Common-mistake #1).
template <int K>
__device__ __forceinline__ void stage_bsw(const u16* __restrict__ Bsw, u16* Bs, int tid) {
  constexpr int PASSES = (K * 256) / 4096;  // 4096 B per 256-thread pass
  int w = tid >> 6, lane = tid & 63;
#pragma unroll
  for (int i = 0; i < PASSES; ++i) {
    int off = i * 4096 + w * 1024;
    __builtin_amdgcn_global_load_lds(
        (const __attribute__((address_space(1))) u32*)((const char*)Bsw + off + lane * 16),
        (__attribute__((address_space(3))) u32*)((char*)Bs + off), 16, 0, 0);
  }
}

// ---------------- MFMA GEMM core: B from LDS, depth-2 A prefetch ----------------
template <int K, int ISBF>
__device__ __forceinline__ void gemm_core(const void* __restrict__ Xv,
                                          const u16* Bs,
                                          const int* mclamp, int q, int lane,
                                          float4v acc[2][8]) {
  constexpr int NT = K / 32;
  const uint4* btb = (const uint4*)Bs + lane;
  if (ISBF) {
    const u16* X0 = (const u16*)Xv + (size_t)mclamp[0] * K + q * 8;
    const u16* X1 = (const u16*)Xv + (size_t)mclamp[1] * K + q * 8;
    short8 a0 = *(const short8*)X0;
    short8 a1 = *(const short8*)X1;
#pragma unroll
    for (int t = 0; t < NT; ++t) {
      short8 n0 = a0, n1 = a1;
      if (t + 1 < NT) {
        n0 = *(const short8*)(X0 + (t + 1) * 32);
        n1 = *(const short8*)(X1 + (t + 1) * 32);
      }
      const uint4* bt = btb + (size_t)t * 8 * 64;
#pragma unroll
      for (int c = 0; c < 8; ++c) {
        uint4 bw = bt[c * 64];  // ds_read_b128
        short8 bf = *(short8*)&bw;
        acc[0][c] = __builtin_amdgcn_mfma_f32_16x16x32_bf16(a0, bf, acc[0][c], 0, 0, 0);
        acc[1][c] = __builtin_amdgcn_mfma_f32_16x16x32_bf16(a1, bf, acc[1][c], 0, 0, 0);
      }
      a0 = n0;
      a1 = n1;
    }
  } else {
    const float* X0 = (const float*)Xv + (size_t)mclamp[0] * K + q * 8;
    const float* X1 = (const float*)Xv + (size_t)mclamp[1] * K + q * 8;
    float4 f00 = *(const float4*)X0, f01 = *(const float4*)(X0 + 4);
    float4 f10 = *(const float4*)X1, f11 = *(const float4*)(X1 + 4);
#pragma unroll
    for (int t = 0; t < NT; ++t) {
      float4 g00 = f00, g01 = f01, g10 = f10, g11 = f11;
      if (t + 1 < NT) {
        g00 = *(const float4*)(X0 + (t + 1) * 32);
        g01 = *(const float4*)(X0 + (t + 1) * 32 + 4);
        g10 = *(const float4*)(X1 + (t + 1) * 32);
        g11 = *(const float4*)(X1 + (t + 1) * 32 + 4);
      }
      u16 t0[8] = {f2bf(f00.x), f2bf(f00.y), f2bf(f00.z), f2bf(f00.w),
                   f2bf(f01.x), f2bf(f01.y), f2bf(f01.z), f2bf(f01.w)};
      u16 t1[8] = {f2bf(f10.x), f2bf(f10.y), f2bf(f10.z), f2bf(f10.w),
                   f2bf(f11.x), f2bf(f11.y), f2bf(f11.z), f2bf(f11.w)};
      short8 a0 = *(short8*)t0;
      short8 a1 = *(short8*)t1;
      const uint4* bt = btb + (size_t)t * 8 * 64;
#pragma unroll
      for (int c = 0; c < 8; ++c) {
        uint4 bw = bt[c * 64];
        short8 bf = *(short8*)&bw;
        acc[0][c] = __builtin_amdgcn_mfma_f32_16x16x32_bf16(a0, bf, acc[0][c], 0, 0, 0);
        acc[1][c] = __builtin_amdgcn_mfma_f32_16x16x32_bf16(a1, bf, acc[1][c], 0, 0, 0);
      }
      f00 = g00; f01 = g01; f10 = g10; f11 = g11;
    }
  }
}

// ---------------- MFMA GEMM body: 32 rows/wave (2 row-tiles), 128 rows/block ----
template <int K, int DYNA>
__device__ __forceinline__ void gemm_body(int bix, const void* __restrict__ Xv,
                                          const u16* __restrict__ Bsw,
                                          u16* __restrict__ Hb,
                                          const void* __restrict__ al,
                                          const void* __restrict__ ar,
                                          float* __restrict__ el_,
                                          float* __restrict__ er_, int N,
                                          const int* __restrict__ dflag) {
  __shared__ __align__(16) u16 Bs[(K / 32) * 8 * 64 * 8];  // K=256: 64 KB, K=128: 32 KB
  const int isbfP = dflag[0];
  int tid = threadIdx.x;
  int w = tid >> 6, lane = tid & 63;
  int n = lane & 15, q = lane >> 4;
  int base = bix * 128 + w * 32;  // wave covers rows [base, base+32)

  stage_bsw<K>(Bsw, Bs, tid);

  int mclamp[2];
#pragma unroll
  for (int mt = 0; mt < 2; ++mt) {
    int m = base + mt * 16 + n;
    mclamp[mt] = (m < N) ? m : 0;
  }

  float alv[8], arv[8];
#pragma unroll
  for (int c = 0; c < 8; ++c) {
    alv[c] = loadf(al, c * 16 + n, isbfP);
    arv[c] = loadf(ar, c * 16 + n, isbfP);
  }

  float4v acc[2][8];
#pragma unroll
  for (int mt = 0; mt < 2; ++mt)
#pragma unroll
    for (int c = 0; c < 8; ++c) acc[mt][c] = (float4v){0.f, 0.f, 0.f, 0.f};

  __syncthreads();  // drains global_load_lds (vmcnt 0) + barrier

  // x intermediate is always bf16; features dtype is runtime (dflag).
  if (DYNA == 0 || isbfP) {
    gemm_core<K, 1>(Xv, Bs, mclamp, q, lane, acc);
  } else {
    gemm_core<K, 0>(Xv, Bs, mclamp, q, lane, acc);
  }

  // Hb store: D layout col = c*16 + (lane&15), row = base + mt*16 + q*4 + r
#pragma unroll
  for (int mt = 0; mt < 2; ++mt)
#pragma unroll
    for (int c = 0; c < 8; ++c) {
#pragma unroll
      for (int r = 0; r < 4; ++r) {
        int row = base + mt * 16 + q * 4 + r;
        if (row < N) Hb[(size_t)row * 128 + c * 16 + n] = f2bf(acc[mt][c][r]);
      }
    }

  // fused el/er: reduce across the 16 lanes of each quad-row group
#pragma unroll
  for (int mt = 0; mt < 2; ++mt)
#pragma unroll
    for (int r = 0; r < 4; ++r) {
      float sl = 0.f, sr = 0.f;
#pragma unroll
      for (int c = 0; c < 8; ++c) {
        float v = acc[mt][c][r];
        sl = fmaf(v, alv[c], sl);
        sr = fmaf(v, arv[c], sr);
      }
#pragma unroll
      for (int off = 1; off < 16; off <<= 1) {
        sl += __shfl_xor(sl, off);
        sr += __shfl_xor(sr, off);
      }
      if (n == 0) {
        int row = base + mt * 16 + q * 4 + r;
        if (row < N) {
          el_[row] = sl;
          er_[row] = sr;
        }
      }
    }
}

template <int K, int DYNA>
__global__ __launch_bounds__(256) void gemm_mfma(const void* __restrict__ Xv,
                                                 const u16* __restrict__ Bsw,
                                                 u16* __restrict__ Hb,
                                                 const void* __restrict__ al,
                                                 const void* __restrict__ ar,
                                                 float* __restrict__ el_,
                                                 float* __restrict__ er_, int N,
                                                 const int* __restrict__ dflag) {
  gemm_body<K, DYNA>(blockIdx.x, Xv, Bsw, Hb, al, ar, el_, er_, N, dflag);
}

// fused: blocks [0, gemm_blocks) do GEMM layer 1; the rest do the coarse
// histogram (P1a) of the counting-sort CSR build — LDS atomics only.
template <int K, int DYNA>
__global__ __launch_bounds__(256) void fused_gemm_hist(
    const void* __restrict__ Xv, const u16* __restrict__ Bsw, u16* __restrict__ Hb,
    const void* __restrict__ al, const void* __restrict__ ar,
    float* __restrict__ el_, float* __restrict__ er_, int N,
    const int* __restrict__ dflag, int gemm_blocks,
    const int* __restrict__ dst, int* __restrict__ Gh, int E, int PB, int nbuck) {
  __shared__ int hcnt[MAXBUCK];
  int bix = (int)blockIdx.x;
  if (bix < gemm_blocks) {
    gemm_body<K, DYNA>(bix, Xv, Bsw, Hb, al, ar, el_, er_, N, dflag);
    return;
  }
  int pblk = bix - gemm_blocks;
  int t = threadIdx.x;
  for (int i = t; i < nbuck; i += 256) hcnt[i] = 0;
  __syncthreads();
  int pbase = pblk * 4096;
#pragma unroll
  for (int j = 0; j < 16; ++j) {
    int e = pbase + j * 256 + t;
    if (e < E) {
      u32 b = (u32)dst[e] >> BSHIFT;
      if (b < (u32)nbuck) atomicAdd(&hcnt[b], 1);
    }
  }
  __syncthreads();
  for (int i = t; i < nbuck; i += 256) Gh[(size_t)i * PB + pblk] = hcnt[i];
}

// ---------------- aggregation: wave-parallel softmax ----------------
// r9: fast path for deg<=64 (always, for this graph: mean degree 16) — single
// pass, no online-rescale state; float2 ext-vector accumulate (v_pk_fma_f32
// candidate). General chunked path retained for deg>64.
template <int MODE>
__global__ __launch_bounds__(256) void agg_kernel(const u32* __restrict__ Hb,
                                                  const float* __restrict__ el,
                                                  const float* __restrict__ er,
                                                  const int* __restrict__ indptr,
                                                  const int* __restrict__ ssrc,
                                                  const void* __restrict__ bias,
                                                  void* __restrict__ outv, int N,
                                                  const int* __restrict__ dflag) {
  const int isbf = dflag[0];
  int tid = threadIdx.x;
  int n = blockIdx.x * 4 + (tid >> 6);
  int lane = tid & 63;
  if (n >= N) return;

  int beg = indptr[n];
  int end = indptr[n + 1];
  int deg = end - beg;
  float ern = er[n];

  float2v acc = {0.f, 0.f};
  float inv;

  if (deg <= 64) {
    int valid = lane < deg;
    int ide = valid ? ssrc[beg + lane] : 0;
    float sc = el[ide] + ern;
    sc = (sc > 0.f) ? sc : NEG_SLOPE * sc;
    sc = valid ? sc : -INFINITY;

    float m = sc;
#pragma unroll
    for (int off = 1; off < 64; off <<= 1) m = fmaxf(m, __shfl_xor(m, off));
    float pe = __expf(sc - m);  // deg==0: nan in dead registers only
    float l = pe;
#pragma unroll
    for (int off = 1; off < 64; off <<= 1) l += __shfl_xor(l, off);

    int e = 0;
    for (; e + 8 <= deg; e += 8) {
      int id_[8];
      u32 h_[8];
#pragma unroll
      for (int k = 0; k < 8; ++k) id_[k] = __builtin_amdgcn_readlane(ide, e + k);
#pragma unroll
      for (int k = 0; k < 8; ++k) h_[k] = Hb[(size_t)id_[k] * 64 + lane];
#pragma unroll
      for (int k = 0; k < 8; ++k) {
        float pk = __int_as_float(__builtin_amdgcn_readlane(__float_as_int(pe), e + k));
        float2v hv = {bflo(h_[k]), bfhi(h_[k])};
        float2v pv = {pk, pk};
        acc = pv * hv + acc;
      }
    }
    for (; e + 4 <= deg; e += 4) {
      int id_[4];
      u32 h_[4];
#pragma unroll
      for (int k = 0; k < 4; ++k) id_[k] = __builtin_amdgcn_readlane(ide, e + k);
#pragma unroll
      for (int k = 0; k < 4; ++k) h_[k] = Hb[(size_t)id_[k] * 64 + lane];
#pragma unroll
      for (int k = 0; k < 4; ++k) {
        float pk = __int_as_float(__builtin_amdgcn_readlane(__float_as_int(pe), e + k));
        float2v hv = {bflo(h_[k]), bfhi(h_[k])};
        float2v pv = {pk, pk};
        acc = pv * hv + acc;
      }
    }
    for (; e < deg; ++e) {
      int i0 = __builtin_amdgcn_readlane(ide, e);
      u32 h0 = Hb[(size_t)i0 * 64 + lane];
      float pk = __int_as_float(__builtin_amdgcn_readlane(__float_as_int(pe), e));
      float2v hv = {bflo(h0), bfhi(h0)};
      float2v pv = {pk, pk};
      acc = pv * hv + acc;
    }
    inv = (deg > 0 && l > 0.f) ? 1.f / l : 0.f;
  } else {
    // general chunked online-softmax path (deg > 64)
    float m_run = -INFINITY, l_run = 0.f;
    for (int p = beg; p < end; p += 64) {
      int rem = end - p;
      int valid = lane < rem;
      int ide = valid ? ssrc[p + lane] : 0;
      float sc = el[ide] + ern;
      sc = (sc > 0.f) ? sc : NEG_SLOPE * sc;
      sc = valid ? sc : -INFINITY;
      float mc = sc;
#pragma unroll
      for (int off = 1; off < 64; off <<= 1) mc = fmaxf(mc, __shfl_xor(mc, off));
      float m_new = fmaxf(m_run, mc);
      float corr = __expf(m_run - m_new);
      float pe = __expf(sc - m_new);
      float ls = pe;
#pragma unroll
      for (int off = 1; off < 64; off <<= 1) ls += __shfl_xor(ls, off);
      l_run = l_run * corr + ls;
      float2v cv = {corr, corr};
      acc = acc * cv;
      m_run = m_new;

      int cl = (rem < 64) ? rem : 64;
      int e = 0;
      for (; e + 8 <= cl; e += 8) {
        int id_[8];
        u32 h_[8];
#pragma unroll
        for (int k = 0; k < 8; ++k) id_[k] = __builtin_amdgcn_readlane(ide, e + k);
#pragma unroll
        for (int k = 0; k < 8; ++k) h_[k] = Hb[(size_t)id_[k] * 64 + lane];
#pragma unroll
        for (int k = 0; k < 8; ++k) {
          float pk = __int_as_float(__builtin_amdgcn_readlane(__float_as_int(pe), e + k));
          float2v hv = {bflo(h_[k]), bfhi(h_[k])};
          float2v pv = {pk, pk};
          acc = pv * hv + acc;
        }
      }
      for (; e < cl; ++e) {
        int i0 = __builtin_amdgcn_readlane(ide, e);
        u32 h0 = Hb[(size_t)i0 * 64 + lane];
        float pk = __int_as_float(__builtin_amdgcn_readlane(__float_as_int(pe), e));
        float2v hv = {bflo(h0), bfhi(h0)};
        float2v pv = {pk, pk};
        acc = pv * hv + acc;
      }
    }
    inv = (l_run > 0.f) ? 1.f / l_run : 0.f;
  }

  float o0 = acc.x * inv + loadf(bias, 2 * lane, isbf);
  float o1 = acc.y * inv + loadf(bias, 2 * lane + 1, isbf);

  if (MODE == 0) {
    o0 = (o0 > 0.f) ? o0 : (__expf(o0) - 1.f);
    o1 = (o1 > 0.f) ? o1 : (__expf(o1) - 1.f);
    ((u32*)outv)[(size_t)n * 64 + lane] = (u32)f2bf(o0) | ((u32)f2bf(o1) << 16);
  } else {
    if (isbf) {
      ((u32*)outv)[(size_t)n * 64 + lane] = (u32)f2bf(o0) | ((u32)f2bf(o1) << 16);
    } else {
      ((float2*)outv)[(size_t)n * 64 + lane] = make_float2(o0, o1);
    }
  }
}

// ---------------- launch ----------------

extern "C" void kernel_launch(void* const* d_in, const int* in_sizes, int n_in,
                              void* d_out, int out_size, void* d_ws, size_t ws_size,
                              hipStream_t stream) {
  const int IN_FEATS = 256, HID = 128;
  const void* features = d_in[0];
  const int* src = (const int*)d_in[1];
  const int* dst = (const int*)d_in[2];
  const void* W1 = d_in[3];
  const void* al1 = d_in[4];
  const void* ar1 = d_in[5];
  const void* b1 = d_in[6];
  const void* W2 = d_in[7];
  const void* al2 = d_in[8];
  const void* ar2 = d_in[9];
  const void* b2 = d_in[10];

  const int N = in_sizes[0] / IN_FEATS;  // 100000
  const int E = in_sizes[1];             // 1600000

  char* p = (char*)d_ws;
  auto alloc = [&](size_t bytes) -> void* {
    void* q = (void*)p;
    p += (bytes + 255) & ~(size_t)255;
    return q;
  };
  int* dflag = (int*)alloc(256);
  u16* Bsw1 = (u16*)alloc((size_t)(IN_FEATS / 32) * 8 * 64 * 8 * 2);  // 64 KB
  u16* Bsw2 = (u16*)alloc((size_t)(HID / 32) * 8 * 64 * 8 * 2);       // 32 KB
  u16* hb = (u16*)alloc((size_t)N * HID * 2);  // 25.6 MB
  u16* x = (u16*)alloc((size_t)N * HID * 2);   // 25.6 MB
  float* el = (float*)alloc((size_t)N * 4);
  float* er = (float*)alloc((size_t)N * 4);
  int* indptr = (int*)alloc((size_t)(N + 1) * 4);

  const int nbuck = (N + 255) >> BSHIFT;  // 391
  const int PB = (E + 4095) / 4096;       // 391 (4096 edges per P1 block)
  const int M = nbuck * PB;               // 152881
  const int MB1 = (M + 255) / 256;        // 598

  int* Gh = (int*)alloc((size_t)M * 4);       // 0.6 MB
  int* bsumA = (int*)alloc((size_t)MB1 * 4);  // 2.4 KB
  int* ssrc = (int*)alloc((size_t)E * 4);     // 6.4 MB

  // pd/ps ALIAS the x buffer (workspace safety): pd/ps are dead after
  // bucket_sort completes; x is first written by agg_kernel<0>, which is
  // stream-ordered strictly after bucket_sort. 2*E*4 = 12.8 MB < 25.6 MB.
  int* pd = (int*)x;
  int* ps = (int*)((char*)x + (((size_t)E * 4 + 255) & ~(size_t)255));

  const int GEMM_B = (N + 127) / 128;  // 782 (128 rows/block)
  const int NODE_B = (N + 3) / 4;      // 25000

  detect_dtype<<<1, 256, 0, stream>>>((const u32*)features, 4096, dflag);
  bsw_build<<<((IN_FEATS / 32) * 8 * 64 + 255) / 256, 256, 0, stream>>>(W1, Bsw1, IN_FEATS, dflag);
  bsw_build<<<((HID / 32) * 8 * 64 + 255) / 256, 256, 0, stream>>>(W2, Bsw2, HID, dflag);

  // GEMM layer 1 (+ fused el/er) co-scheduled with the coarse histogram
  fused_gemm_hist<IN_FEATS, 1><<<GEMM_B + PB, 256, 0, stream>>>(
      features, Bsw1, hb, al1, ar1, el, er, N, dflag, GEMM_B, dst, Gh, E, PB, nbuck);

  // scan Gh (bucket-major): per-256-block exclusive + block sums (boff applied
  // on the fly by part_scatter/bucket_sort — scanC eliminated)
  scanA<<<MB1, 256, 0, stream>>>(Gh, bsumA, M);
  scanBseq<<<1, 512, 0, stream>>>(bsumA, MB1);

  // partition edges into coarse-bucket-major order, then fine-sort per bucket
  part_scatter<<<PB, 256, 0, stream>>>(src, dst, Gh, bsumA, pd, ps, E, PB, nbuck);
  bucket_sort<<<nbuck, 256, 0, stream>>>(pd, ps, Gh, bsumA, indptr, ssrc, E, N, PB, nbuck);

  agg_kernel<0><<<NODE_B, 256, 0, stream>>>((const u32*)hb, el, er, indptr, ssrc, b1, (void*)x, N, dflag);

  gemm_mfma<HID, 0><<<GEMM_B, 256, 0, stream>>>((const void*)x, Bsw2, hb, al2, ar2, el, er, N, dflag);
  agg_kernel<1><<<NODE_B, 256, 0, stream>>>((const u32*)hb, el, er, indptr, ssrc, b2, d_out, N, dflag);
}